// Round 2
// baseline (347.466 us; speedup 1.0000x reference)
//
#include <hip/hip_runtime.h>
#include <hip/hip_bf16.h>
#include <type_traits>

// MultiHead attention, MI355X/gfx950. Inputs/output fp32 (per reference);
// internal compute bf16 MFMA with fp32 accumulate (comparison is at bf16
// tolerance: threshold = 2% of max|ref|).
// B=2, T=2048, C=1024, H=16, D=64.
// ws layout: qkv [3][16][4096][64] bf16 (25.2MB) | att [4096][1024] bf16 (8.4MB)

typedef __hip_bfloat16 bf16;
typedef __bf16 v8bf __attribute__((ext_vector_type(8)));
typedef float  v4f  __attribute__((ext_vector_type(4)));

#define MFMA16(a, b, c) __builtin_amdgcn_mfma_f32_16x16x32_bf16((a), (b), (c), 0, 0, 0)

__device__ __forceinline__ float b2f(bf16 x) { return __bfloat162float(x); }
__device__ __forceinline__ bf16  f2b(float x) { return __float2bfloat16(x); }

// ---------------------------------------------------------------------------
// 128x64 GEMM tile: out[128x64] = A[128xK] * B[Kx64] * scale (+ bias)
// A row-major (lda): fp32 or bf16. B row-major (ldb): fp32 (converted during
// staging). out: bf16 (OT=bf16) or fp32 (OT=float, with fp32 bias).
// Block = 256 threads. Fragment layouts (measured, guide §3):
// A: m=lane&15, k=quad*8+j; B: n=lane&15, same k; C/D: col=lane&15, row=quad*4+r.
// ---------------------------------------------------------------------------
template <typename AT, typename OT>
__device__ __forceinline__ void gemm_tile_128x64(
    const AT* __restrict__ A, int lda,
    const float* __restrict__ B, int ldb,
    OT* __restrict__ out, int ldc,
    int K, float scale, const float* __restrict__ bias)
{
  // stride 40 bf16 = 80B: 16B-aligned rows, 2-way bank aliasing only (free)
  __shared__ __align__(16) bf16 Ash[128][40];
  __shared__ __align__(16) bf16 Bsh[64][40];   // transposed: Bsh[n][k]

  const int tid  = threadIdx.x;
  const int w    = tid >> 6;
  const int lane = tid & 63;
  const int ln   = lane & 15;
  const int quad = lane >> 4;

  const v4f vzero = {0.f, 0.f, 0.f, 0.f};
  v4f acc[2][4];
  #pragma unroll
  for (int s = 0; s < 2; ++s)
    #pragma unroll
    for (int n = 0; n < 4; ++n) acc[s][n] = vzero;

  const int am = tid >> 1;             // 0..127 (A stage row)
  const int ak = (tid & 1) * 16;       // 0/16   (A stage k-seg)
  const int bk = tid >> 3;             // 0..31  (B stage k)
  const int bn = (tid & 7) * 8;        // 0..56  (B stage n-seg)

  for (int k0 = 0; k0 < K; k0 += 32) {
    __syncthreads();
    {   // stage A tile 128x32
      if constexpr (std::is_same<AT, float>::value) {
        const float* src = A + (size_t)am * lda + k0 + ak;
        #pragma unroll
        for (int i = 0; i < 4; ++i) {
          float4 f = *(const float4*)(src + i * 4);
          Ash[am][ak + i * 4 + 0] = f2b(f.x);
          Ash[am][ak + i * 4 + 1] = f2b(f.y);
          Ash[am][ak + i * 4 + 2] = f2b(f.z);
          Ash[am][ak + i * 4 + 3] = f2b(f.w);
        }
      } else {
        const bf16* src = (const bf16*)A + (size_t)am * lda + k0 + ak;
        v8bf a0 = *(const v8bf*)(src);
        v8bf a1 = *(const v8bf*)(src + 8);
        *(v8bf*)&Ash[am][ak]     = a0;
        *(v8bf*)&Ash[am][ak + 8] = a1;
      }
    }
    {   // stage B tile 32x64 transposed, fp32 -> bf16
      const float* src = B + (size_t)(k0 + bk) * ldb + bn;
      float4 q0 = *(const float4*)(src);
      float4 q1 = *(const float4*)(src + 4);
      Bsh[bn + 0][bk] = f2b(q0.x);
      Bsh[bn + 1][bk] = f2b(q0.y);
      Bsh[bn + 2][bk] = f2b(q0.z);
      Bsh[bn + 3][bk] = f2b(q0.w);
      Bsh[bn + 4][bk] = f2b(q1.x);
      Bsh[bn + 5][bk] = f2b(q1.y);
      Bsh[bn + 6][bk] = f2b(q1.z);
      Bsh[bn + 7][bk] = f2b(q1.w);
    }
    __syncthreads();

    v8bf af[2], bfr[4];
    #pragma unroll
    for (int s = 0; s < 2; ++s)
      af[s] = *(const v8bf*)&Ash[w * 32 + s * 16 + ln][quad * 8];
    #pragma unroll
    for (int n = 0; n < 4; ++n)
      bfr[n] = *(const v8bf*)&Bsh[n * 16 + ln][quad * 8];
    #pragma unroll
    for (int s = 0; s < 2; ++s)
      #pragma unroll
      for (int n = 0; n < 4; ++n)
        acc[s][n] = MFMA16(af[s], bfr[n], acc[s][n]);
  }

  // epilogue: C/D layout col=lane&15, row=quad*4+r
  #pragma unroll
  for (int s = 0; s < 2; ++s)
    #pragma unroll
    for (int n = 0; n < 4; ++n)
      #pragma unroll
      for (int r = 0; r < 4; ++r) {
        int row = w * 32 + s * 16 + quad * 4 + r;
        int col = n * 16 + ln;
        float v = acc[s][n][r] * scale;
        if (bias) v += bias[col];
        if constexpr (std::is_same<OT, float>::value) {
          out[(size_t)row * ldc + col] = v;
        } else {
          ((bf16*)out)[(size_t)row * ldc + col] = f2b(v);
        }
      }
}

// ---------------------------------------------------------------------------
// Kernel 1: QKV projections. grid=(32, 48): x=M-tile(128 rows), y=proj*16+head.
// q scaled by 1/sqrt(C)=1/32 at store. qkv layout [proj][h][m=b*T+t][d] bf16.
// ---------------------------------------------------------------------------
__global__ __launch_bounds__(256) void qkv_proj_kernel(
    const float* __restrict__ x,
    const float* __restrict__ Wq, const float* __restrict__ Wk,
    const float* __restrict__ Wv,
    bf16* __restrict__ qkv)
{
  const int mt = blockIdx.x;
  const int y  = blockIdx.y;
  const int proj = y >> 4, h = y & 15;
  const float* W = (proj == 0) ? Wq : (proj == 1) ? Wk : Wv;
  const float* A = x + (size_t)mt * 128 * 1024;
  bf16* out = qkv + ((size_t)(proj * 16 + h)) * (4096 * 64) + (size_t)mt * 128 * 64;
  const float scale = (proj == 0) ? 0.03125f : 1.0f;
  gemm_tile_128x64<float, bf16>(A, 1024, W + (size_t)h * 65536, 64, out, 64,
                                1024, scale, nullptr);
}

// ---------------------------------------------------------------------------
// Kernel 2: causal flash attention. grid=(32, 32): x=Q-tile(64 rows), y=b*16+h.
// Block = 4 waves x 16 Q-rows. K/V tiles of 64 staged in LDS (V transposed);
// P round-trips through per-wave LDS (C/D layout -> A layout). All bf16 I/O.
// ---------------------------------------------------------------------------
__global__ __launch_bounds__(256) void attn_kernel(
    const bf16* __restrict__ qkv, bf16* __restrict__ att)
{
  // stride 88 bf16 = 176B: 16B-aligned, 2-way bank aliasing (free)
  __shared__ __align__(16) bf16 Ksh[64][88];
  __shared__ __align__(16) bf16 Vsh[64][88];        // transposed: Vsh[d][t']
  __shared__ __align__(16) bf16 Psh[4][16][88];     // per-wave P tile

  const int qb = blockIdx.x;          // Q-tile index (0..31)
  const int bh = blockIdx.y;
  const int b = bh >> 4, h = bh & 15;

  const int tid  = threadIdx.x;
  const int w    = tid >> 6;
  const int lane = tid & 63;
  const int ln   = lane & 15;
  const int quad = lane >> 4;

  const size_t head_off = (size_t)h * (4096 * 64) + (size_t)b * (2048 * 64);
  const bf16* qp = qkv + head_off + (size_t)(qb * 64 + w * 16) * 64;
  const bf16* kp = qkv + (size_t)16 * (4096 * 64) + head_off;
  const bf16* vp = qkv + (size_t)32 * (4096 * 64) + head_off;

  // Q fragments (A-layout), K-dim = D = 64 -> 2 k-steps. Q pre-scaled by 1/32.
  v8bf aq[2];
  aq[0] = *(const v8bf*)(qp + (size_t)ln * 64 + quad * 8);
  aq[1] = *(const v8bf*)(qp + (size_t)ln * 64 + 32 + quad * 8);

  const v4f vzero = {0.f, 0.f, 0.f, 0.f};
  v4f o[4];
  #pragma unroll
  for (int n = 0; n < 4; ++n) o[n] = vzero;
  const float NEG = -30000.0f;   // safe -inf surrogate (exp underflows to 0)
  float m_i[4] = {NEG, NEG, NEG, NEG};
  float l_i[4] = {0.f, 0.f, 0.f, 0.f};

  const int sr = tid >> 2;            // 0..63 staging row
  const int sc = (tid & 3) * 16;      // 0,16,32,48 staging col seg

  for (int kb = 0; kb <= qb; ++kb) {
    __syncthreads();                  // protect K/V LDS from prev iteration
    {
      const bf16* ks = kp + (size_t)(kb * 64 + sr) * 64 + sc;
      v8bf k0 = *(const v8bf*)(ks);
      v8bf k1 = *(const v8bf*)(ks + 8);
      *(v8bf*)&Ksh[sr][sc]     = k0;
      *(v8bf*)&Ksh[sr][sc + 8] = k1;
      const bf16* vs = vp + (size_t)(kb * 64 + sr) * 64 + sc;
      v8bf v0 = *(const v8bf*)(vs);
      v8bf v1 = *(const v8bf*)(vs + 8);
      #pragma unroll
      for (int j = 0; j < 8; ++j) Vsh[sc + j][sr]     = ((const bf16*)&v0)[j];
      #pragma unroll
      for (int j = 0; j < 8; ++j) Vsh[sc + 8 + j][sr] = ((const bf16*)&v1)[j];
    }
    __syncthreads();

    // S = Q K^T  (K rows read in A-layout = B-fragment of K^T)
    v4f s[4];
    #pragma unroll
    for (int n = 0; n < 4; ++n) s[n] = vzero;
    #pragma unroll
    for (int ks2 = 0; ks2 < 2; ++ks2) {
      #pragma unroll
      for (int n = 0; n < 4; ++n) {
        v8bf bk = *(const v8bf*)&Ksh[n * 16 + ln][ks2 * 32 + quad * 8];
        s[n] = MFMA16(aq[ks2], bk, s[n]);
      }
    }

    // causal mask on the diagonal tile
    if (kb == qb) {
      #pragma unroll
      for (int n = 0; n < 4; ++n)
        #pragma unroll
        for (int r = 0; r < 4; ++r) {
          int col = n * 16 + ln;
          int row = w * 16 + quad * 4 + r;
          if (col > row) s[n][r] = NEG;
        }
    }

    // online softmax: rows owned per C/D layout (quad*4+r), cols across 16 lanes
    #pragma unroll
    for (int r = 0; r < 4; ++r) {
      float mx = fmaxf(fmaxf(s[0][r], s[1][r]), fmaxf(s[2][r], s[3][r]));
      mx = fmaxf(mx, __shfl_xor(mx, 1));
      mx = fmaxf(mx, __shfl_xor(mx, 2));
      mx = fmaxf(mx, __shfl_xor(mx, 4));
      mx = fmaxf(mx, __shfl_xor(mx, 8));
      float mn = fmaxf(m_i[r], mx);
      float al = expf(m_i[r] - mn);
      m_i[r] = mn;
      float rs = 0.f;
      #pragma unroll
      for (int n = 0; n < 4; ++n) {
        float p = expf(s[n][r] - mn);
        s[n][r] = p;
        rs += p;
      }
      rs += __shfl_xor(rs, 1);
      rs += __shfl_xor(rs, 2);
      rs += __shfl_xor(rs, 4);
      rs += __shfl_xor(rs, 8);
      l_i[r] = l_i[r] * al + rs;
      #pragma unroll
      for (int n = 0; n < 4; ++n) o[n][r] *= al;
    }

    // P (C/D layout) -> per-wave LDS -> A-layout fragments
    #pragma unroll
    for (int n = 0; n < 4; ++n)
      #pragma unroll
      for (int r = 0; r < 4; ++r)
        Psh[w][quad * 4 + r][n * 16 + ln] = f2b(s[n][r]);
    __asm__ volatile("s_waitcnt lgkmcnt(0)" ::: "memory");  // same-wave LDS RAW

    // O += P * V   (V read from transposed tile)
    #pragma unroll
    for (int ks2 = 0; ks2 < 2; ++ks2) {
      v8bf ap = *(const v8bf*)&Psh[w][ln][ks2 * 32 + quad * 8];
      #pragma unroll
      for (int n = 0; n < 4; ++n) {
        v8bf bv = *(const v8bf*)&Vsh[n * 16 + ln][ks2 * 32 + quad * 8];
        o[n] = MFMA16(ap, bv, o[n]);
      }
    }
  }

  // epilogue: normalize by l, write att[b*T + t][h*64 + d] (bf16)
  #pragma unroll
  for (int n = 0; n < 4; ++n)
    #pragma unroll
    for (int r = 0; r < 4; ++r) {
      int row = qb * 64 + w * 16 + quad * 4 + r;
      int col = h * 64 + n * 16 + ln;
      float v = o[n][r] / l_i[r];
      att[((size_t)(b * 2048 + row)) * 1024 + col] = f2b(v);
    }
}

// ---------------------------------------------------------------------------
// Kernel 3: output projection + fp32 bias, fp32 output.
// grid=(32,16): x=M-tile(128), y=N-tile of 64.
// ---------------------------------------------------------------------------
__global__ __launch_bounds__(256) void out_proj_kernel(
    const bf16* __restrict__ att, const float* __restrict__ Wo,
    const float* __restrict__ bo, float* __restrict__ out)
{
  const int mt = blockIdx.x;
  const int nt = blockIdx.y;
  gemm_tile_128x64<bf16, float>(att + (size_t)mt * 128 * 1024, 1024,
                                Wo + nt * 64, 1024,
                                out + (size_t)mt * 128 * 1024 + nt * 64, 1024,
                                1024, 1.0f, bo + nt * 64);
}

extern "C" void kernel_launch(void* const* d_in, const int* in_sizes, int n_in,
                              void* d_out, int out_size, void* d_ws, size_t ws_size,
                              hipStream_t stream) {
  const float* x  = (const float*)d_in[0];
  const float* Wq = (const float*)d_in[1];
  const float* Wk = (const float*)d_in[2];
  const float* Wv = (const float*)d_in[3];
  const float* Wo = (const float*)d_in[4];
  const float* bo = (const float*)d_in[5];
  float* out = (float*)d_out;

  bf16* qkv = (bf16*)d_ws;                          // [3][16][4096][64]
  bf16* att = qkv + (size_t)3 * 16 * 4096 * 64;     // [4096][1024]

  qkv_proj_kernel<<<dim3(32, 48), 256, 0, stream>>>(x, Wq, Wk, Wv, qkv);
  attn_kernel   <<<dim3(32, 32), 256, 0, stream>>>(qkv, att);
  out_proj_kernel<<<dim3(32, 16), 256, 0, stream>>>(att, Wo, bo, out);
}